// Round 5
// baseline (161.096 us; speedup 1.0000x reference)
//
#include <hip/hip_runtime.h>

typedef float f32x4 __attribute__((ext_vector_type(4)));
typedef _Float16 half8 __attribute__((ext_vector_type(8)));

#define SEQ_LEN 32
#define EMBED_DIM 64
#define FC_DIM 100
#define BATCH 512
#define AS2 136     // f16 row stride for A_s2/B_s2 (272 B, 16B-aligned)
#define ES 72       // f16 row stride for emb_s (144 B, 16B-aligned)

union H8 { uint4 u4; half8 v; _Float16 h[8]; };

__device__ __forceinline__ half8 relu8(half8 s) {
#if __has_builtin(__builtin_elementwise_max)
  half8 zero = {};
  return __builtin_elementwise_max(s, zero);
#else
  half8 r;
  #pragma unroll
  for (int j = 0; j < 8; ++j) r[j] = s[j] > (_Float16)0.f ? s[j] : (_Float16)0.f;
  return r;
#endif
}

// All global float tensors are fp32 (JAX default dtypes). f16 used internally
// for MFMA fragments + the h1 intermediate; all accumulation fp32.
//
// One block per batch element. 256 threads = 4 waves. m-tiles (pairs of
// (a, c-half)) partitioned across waves; n (FC_DIM out of layer 2) covered in
// TWO passes (nt 0..3, then 4..6) so the register-resident Wf2 fragment set is
// only 64 VGPRs per pass (round-3's 112-VGPR wfrag is the presumed spill cause
// of the 160 us result).
template<int NT0, int NT>
__device__ __forceinline__ void run_pass(
    const float* __restrict__ Wf2, const float* __restrict__ bf2,
    const _Float16* A_s2, const _Float16* B_s2,
    int w, int l15, int q, float* colsum)
{
  H8 wfrag[NT][4];
  float bf2r[NT];
  #pragma unroll
  for (int n = 0; n < NT; ++n) {
    const int gg = (NT0 + n) * 16 + l15;
    #pragma unroll
    for (int ks = 0; ks < 4; ++ks) {
      const int f0 = ks * 32 + q * 8;
      if (gg < FC_DIM && ks < 3) {          // f0+7 <= 95, 16B-aligned fp32 loads
        const float4 u0 = *(const float4*)(Wf2 + gg * FC_DIM + f0);
        const float4 u1 = *(const float4*)(Wf2 + gg * FC_DIM + f0 + 4);
        wfrag[n][ks].h[0] = (_Float16)u0.x; wfrag[n][ks].h[1] = (_Float16)u0.y;
        wfrag[n][ks].h[2] = (_Float16)u0.z; wfrag[n][ks].h[3] = (_Float16)u0.w;
        wfrag[n][ks].h[4] = (_Float16)u1.x; wfrag[n][ks].h[5] = (_Float16)u1.y;
        wfrag[n][ks].h[6] = (_Float16)u1.z; wfrag[n][ks].h[7] = (_Float16)u1.w;
      } else {
        #pragma unroll
        for (int j = 0; j < 8; ++j) {
          const int f = f0 + j;
          wfrag[n][ks].h[j] = (gg < FC_DIM && f < FC_DIM)
                                  ? (_Float16)Wf2[gg * FC_DIM + f] : (_Float16)0.f;
        }
      }
    }
    bf2r[n] = (gg < FC_DIM) ? bf2[gg] : 0.f;
  }

  for (int g = w; g < 8; g += 4) {          // 2 m-tile groups per wave
    const int c = (g & 1) * 16 + l15;       // lane's c-row (MFMA m-index)
    const int a0 = (g >> 1) * 8;
    H8 areg[4];
    #pragma unroll
    for (int ks = 0; ks < 4; ++ks)
      areg[ks].u4 = *(const uint4*)(A_s2 + c * AS2 + ks * 32 + q * 8);
    for (int ai = 0; ai < 8; ++ai) {
      H8 hf[4];
      #pragma unroll
      for (int ks = 0; ks < 4; ++ks) {
        H8 hb;
        hb.u4 = *(const uint4*)(B_s2 + (a0 + ai) * AS2 + ks * 32 + q * 8);
        hf[ks].v = relu8(areg[ks].v + hb.v);   // v_pk_add_f16 + v_pk_max_f16
      }
      #pragma unroll
      for (int n = 0; n < NT; ++n) {
        f32x4 acc = {0.f, 0.f, 0.f, 0.f};
        #pragma unroll
        for (int ks = 0; ks < 4; ++ks)
          acc = __builtin_amdgcn_mfma_f32_16x16x32_f16(hf[ks].v, wfrag[n][ks].v,
                                                       acc, 0, 0, 0);
        #pragma unroll
        for (int r = 0; r < 4; ++r)
          colsum[NT0 + n] += fmaxf(acc[r] + bf2r[n], 0.f);  // relu2 + M-reduce
      }
    }
  }
}

__global__ __launch_bounds__(256, 2) void cosrec_fused(
    const int* __restrict__ seq_var, const int* __restrict__ user_var,
    const int* __restrict__ item_var, const float* __restrict__ item_emb,
    const float* __restrict__ user_emb, const float* __restrict__ W2,
    const float* __restrict__ b2, const float* __restrict__ W1,
    const float* __restrict__ b1, const float* __restrict__ Wf2,
    const float* __restrict__ bf2, float* __restrict__ out)
{
  __shared__ __align__(16) _Float16 A_s2[SEQ_LEN * AS2];
  __shared__ __align__(16) _Float16 B_s2[SEQ_LEN * AS2];
  __shared__ __align__(16) _Float16 emb_s[SEQ_LEN * ES];
  __shared__ float red_s[16 * 112];
  __shared__ float x_s[112];

  const int b = blockIdx.x;
  const int t = threadIdx.x;
  const int w = t >> 6;
  const int l = t & 63;
  const int l15 = l & 15;
  const int q = l >> 4;

  // ---- Phase A: gather embedding rows, fp32 -> f16 -> LDS ----
  {
    const int r = t >> 3;                 // 0..31
    const int c0 = (t & 7) * 8;
    const int item = seq_var[b * SEQ_LEN + r];
    const float4 v0 = *(const float4*)(item_emb + item * EMBED_DIM + c0);
    const float4 v1 = *(const float4*)(item_emb + item * EMBED_DIM + c0 + 4);
    H8 e;
    e.h[0] = (_Float16)v0.x; e.h[1] = (_Float16)v0.y;
    e.h[2] = (_Float16)v0.z; e.h[3] = (_Float16)v0.w;
    e.h[4] = (_Float16)v1.x; e.h[5] = (_Float16)v1.y;
    e.h[6] = (_Float16)v1.z; e.h[7] = (_Float16)v1.w;
    *(uint4*)(emb_s + r * ES + c0) = e.u4;
  }
  // zero f-pad cols 100..135 of A_s2/B_s2 (MFMA reads to col 127)
  for (int i = t; i < SEQ_LEN * 36; i += 256) {
    const int r = i / 36, c = FC_DIM + (i - r * 36);
    A_s2[r * AS2 + c] = (_Float16)0.f;
    B_s2[r * AS2 + c] = (_Float16)0.f;
  }
  __syncthreads();

  // ---- Phase B: first FC via MFMA (M=32,N=208,K=64), f16 in / fp32 acc ----
  for (int nt = w; nt < 13; nt += 4) {
    const int o = nt * 16 + l15;
    int wr = 0, wc = 0;
    bool valid = true;
    if (o < FC_DIM)          { wr = o;          wc = 0;  }    // Wa = W1[:, :64]
    else if (o < 2 * FC_DIM) { wr = o - FC_DIM; wc = 64; }    // Wb = W1[:, 64:]
    else valid = false;
    H8 bfr[2];
    #pragma unroll
    for (int ks = 0; ks < 2; ++ks) {
      if (valid) {
        const float* p = W1 + wr * 128 + wc + ks * 32 + q * 8;
        const float4 u0 = *(const float4*)p;
        const float4 u1 = *(const float4*)(p + 4);
        bfr[ks].h[0] = (_Float16)u0.x; bfr[ks].h[1] = (_Float16)u0.y;
        bfr[ks].h[2] = (_Float16)u0.z; bfr[ks].h[3] = (_Float16)u0.w;
        bfr[ks].h[4] = (_Float16)u1.x; bfr[ks].h[5] = (_Float16)u1.y;
        bfr[ks].h[6] = (_Float16)u1.z; bfr[ks].h[7] = (_Float16)u1.w;
      } else {
        #pragma unroll
        for (int j = 0; j < 8; ++j) bfr[ks].h[j] = (_Float16)0.f;
      }
    }
    const float b1v = (o >= FC_DIM && o < 2 * FC_DIM) ? b1[o - FC_DIM] : 0.f;
    #pragma unroll
    for (int mt = 0; mt < 2; ++mt) {
      H8 afr[2];
      #pragma unroll
      for (int ks = 0; ks < 2; ++ks)
        afr[ks].u4 = *(const uint4*)(emb_s + (mt * 16 + l15) * ES + ks * 32 + q * 8);
      f32x4 acc = {0.f, 0.f, 0.f, 0.f};
      #pragma unroll
      for (int ks = 0; ks < 2; ++ks)
        acc = __builtin_amdgcn_mfma_f32_16x16x32_f16(afr[ks].v, bfr[ks].v, acc, 0, 0, 0);
      const int row = mt * 16 + q * 4;    // D: col = lane&15, row = quad*4 + reg
      if (o < FC_DIM) {
        #pragma unroll
        for (int r = 0; r < 4; ++r)
          A_s2[(row + r) * AS2 + o] = (_Float16)acc[r];
      } else if (o < 2 * FC_DIM) {
        #pragma unroll
        for (int r = 0; r < 4; ++r)
          B_s2[(row + r) * AS2 + (o - FC_DIM)] = (_Float16)(acc[r] + b1v);
      }
    }
  }
  __syncthreads();

  // ---- Phase D: pair loop, two nt-passes (wfrag = 64 VGPRs per pass) ----
  float colsum[7];
  #pragma unroll
  for (int nt = 0; nt < 7; ++nt) colsum[nt] = 0.f;
  run_pass<0, 4>(Wf2, bf2, A_s2, B_s2, w, l15, q, colsum);
  run_pass<4, 3>(Wf2, bf2, A_s2, B_s2, w, l15, q, colsum);

  // ---- Phase E: reduce colsum across (wave, quad) via LDS ----
  #pragma unroll
  for (int nt = 0; nt < 7; ++nt)
    red_s[(w * 4 + q) * 112 + nt * 16 + l15] = colsum[nt];
  __syncthreads();
  if (t < 112) {
    float s = 0.f;
    #pragma unroll
    for (int r = 0; r < 16; ++r) s += red_s[r * 112 + t];
    x_s[t] = s;
  }
  __syncthreads();

  // ---- Phase F: out[b,w] = b2[iv] + W2[iv,:]·concat(x_s, uemb), pure fp32 ----
  float partial = 0.f;
  if (w < 3) {
    const int iv = item_var[b * 3 + w];
    const int uu = user_var[b];
    for (int idx = l; idx < FC_DIM + EMBED_DIM; idx += 64) {
      const float xv = (idx < FC_DIM)
                           ? x_s[idx]
                           : user_emb[uu * EMBED_DIM + (idx - FC_DIM)];
      partial += W2[iv * (FC_DIM + EMBED_DIM) + idx] * xv;
    }
  }
  red_s[w * 64 + l] = partial;
  __syncthreads();
  if (t < 3) {
    float s = 0.f;
    for (int i = 0; i < 64; ++i) s += red_s[t * 64 + i];
    const int iv = item_var[b * 3 + t];
    out[b * 3 + t] = s + b2[iv];
  }
}

extern "C" void kernel_launch(void* const* d_in, const int* in_sizes, int n_in,
                              void* d_out, int out_size, void* d_ws, size_t ws_size,
                              hipStream_t stream) {
  const int* seq = (const int*)d_in[0];
  const int* usr = (const int*)d_in[1];
  const int* itm = (const int*)d_in[2];
  const float* item_emb = (const float*)d_in[3];
  const float* user_emb = (const float*)d_in[4];
  const float* W2  = (const float*)d_in[5];
  const float* b2  = (const float*)d_in[6];
  const float* W1  = (const float*)d_in[7];
  const float* b1  = (const float*)d_in[8];
  const float* Wf2 = (const float*)d_in[9];
  const float* bf2 = (const float*)d_in[10];
  cosrec_fused<<<BATCH, 256, 0, stream>>>(seq, usr, itm, item_emb, user_emb,
                                          W2, b2, W1, b1, Wf2, bf2,
                                          (float*)d_out);
}